// Round 6
// baseline (377.652 us; speedup 1.0000x reference)
//
#include <hip/hip_runtime.h>

#define AS1 __attribute__((address_space(1)))
#define AS3 __attribute__((address_space(3)))
#define NSLOT 8
#define CHUNK 256
#define PPB 1024

__device__ __forceinline__ void gld_lds16(const float* g, float* l) {
  __builtin_amdgcn_global_load_lds((const AS1 void*)g, (AS3 void*)l, 16, 0, 0);
}
__device__ __forceinline__ void gld_lds4(const void* g, void* l) {
  __builtin_amdgcn_global_load_lds((const AS1 void*)g, (AS3 void*)l, 4, 0, 0);
}

#define WAITVM6  do { asm volatile("s_waitcnt vmcnt(6)" ::: "memory"); __builtin_amdgcn_sched_barrier(0); } while (0)
#define WAITVM0  do { asm volatile("s_waitcnt vmcnt(0)" ::: "memory"); __builtin_amdgcn_sched_barrier(0); } while (0)
#define WAITLGKM do { asm volatile("s_waitcnt lgkmcnt(0)" ::: "memory"); __builtin_amdgcn_sched_barrier(0); } while (0)
#define BAR __builtin_amdgcn_s_barrier()

__global__ void zero_k(float* __restrict__ p, int n) {
  int i = blockIdx.x * blockDim.x + threadIdx.x;
  if (i < n) p[i] = 0.f;
}

// Streams r + ri once. Outputs: zb (u8 argmax), wpair (float2 gated resp),
// pig (global partial sums of ri columns).
__global__ __launch_bounds__(256) void prep_k(
    const float* __restrict__ r, const float* __restrict__ ri,
    unsigned char* __restrict__ zb, float* __restrict__ wpairf,
    float* __restrict__ pig, int n)
{
  __shared__ float lpi[256][33];
  float acc[32];
#pragma unroll
  for (int c = 0; c < 32; ++c) acc[c] = 0.f;

  for (int i = blockIdx.x * blockDim.x + threadIdx.x; i < n;
       i += gridDim.x * blockDim.x) {
    const float4* rr = (const float4*)(r + (size_t)i * 16);
    float4 a0 = rr[0], a1 = rr[1], a2 = rr[2], a3 = rr[3];
    float best = a0.x; int z = 0;
#define CHK(v, c) if ((v) > best) { best = (v); z = (c); }
    CHK(a0.y,1) CHK(a0.z,2) CHK(a0.w,3)
    CHK(a1.x,4) CHK(a1.y,5) CHK(a1.z,6) CHK(a1.w,7)
    CHK(a2.x,8) CHK(a2.y,9) CHK(a2.z,10) CHK(a2.w,11)
    CHK(a3.x,12) CHK(a3.y,13) CHK(a3.z,14) CHK(a3.w,15)
#undef CHK
    const float4* qq = (const float4*)(ri + (size_t)i * 32);
    float4 v0 = qq[0], v1 = qq[1], v2 = qq[2], v3 = qq[3];
    float4 v4 = qq[4], v5 = qq[5], v6 = qq[6], v7 = qq[7];
    acc[0]+=v0.x; acc[1]+=v0.y; acc[2]+=v0.z; acc[3]+=v0.w;
    acc[4]+=v1.x; acc[5]+=v1.y; acc[6]+=v1.z; acc[7]+=v1.w;
    acc[8]+=v2.x; acc[9]+=v2.y; acc[10]+=v2.z; acc[11]+=v2.w;
    acc[12]+=v3.x; acc[13]+=v3.y; acc[14]+=v3.z; acc[15]+=v3.w;
    acc[16]+=v4.x; acc[17]+=v4.y; acc[18]+=v4.z; acc[19]+=v4.w;
    acc[20]+=v5.x; acc[21]+=v5.y; acc[22]+=v5.z; acc[23]+=v5.w;
    acc[24]+=v6.x; acc[25]+=v6.y; acc[26]+=v6.z; acc[27]+=v6.w;
    acc[28]+=v7.x; acc[29]+=v7.y; acc[30]+=v7.z; acc[31]+=v7.w;
    // select ri[2z], ri[2z+1] from registers (cndmask tree)
    int q = z >> 1;
    float4 sel = q < 4 ? (q < 2 ? (q == 0 ? v0 : v1) : (q == 2 ? v2 : v3))
                       : (q < 6 ? (q == 4 ? v4 : v5) : (q == 6 ? v6 : v7));
    float w0 = (z & 1) ? sel.z : sel.x;
    float w1 = (z & 1) ? sel.w : sel.y;
    zb[i] = (unsigned char)z;
    *(float2*)&wpairf[(size_t)i * 2] = make_float2(w0, w1);
  }

#pragma unroll
  for (int c = 0; c < 32; ++c) lpi[threadIdx.x][c] = acc[c];
  __syncthreads();
  if (threadIdx.x < 32) {
    float s = 0.f;
    for (int t = 0; t < 256; ++t) s += lpi[t][threadIdx.x];
    atomicAdd(&pig[threadIdx.x], s);
  }
}

// ---- named-scalar accumulator groups (NO arrays -> cannot go to scratch) ----
#define DECL_GRP(P) \
  float4 P##r0 = make_float4(0,0,0,0), P##r1 = make_float4(0,0,0,0), \
         P##r2 = make_float4(0,0,0,0), P##r3 = make_float4(0,0,0,0), \
         P##m  = make_float4(0,0,0,0); \
  float P##d = 0.f;

#define FMA4(ACC, S, V) \
  ACC.x += (S) * (V).x; ACC.y += (S) * (V).y; \
  ACC.z += (S) * (V).z; ACC.w += (S) * (V).w;

#define UPD_GRP(P, W, X1, X2) { float s_; \
  s_ = (W) * (X1).x; FMA4(P##r0, s_, X2); \
  s_ = (W) * (X1).y; FMA4(P##r1, s_, X2); \
  s_ = (W) * (X1).z; FMA4(P##r2, s_, X2); \
  s_ = (W) * (X1).w; FMA4(P##r3, s_, X2); \
  FMA4(P##m, W, X2); \
  P##d += (W); }

#define CLUSTER_LOOP(KK, A, B) { \
  const int cnt_ = lcnt[buf][KK]; \
  const unsigned char* lk_ = list[buf][KK]; \
  _Pragma("unroll 2") \
  for (int j = 0; j < cnt_; ++j) { \
    int p_ = lk_[j]; \
    float2 wp_ = *(const float2*)&wb[p_ * 2]; \
    float4 x1_ = *(const float4*)&xb[p_ * 32 + g1 * 4]; \
    float4 x2_ = *(const float4*)&xb[p_ * 32 + g2 * 4]; \
    UPD_GRP(A, wp_.x, x1_, x2_); \
    UPD_GRP(B, wp_.y, x1_, x2_); \
  } }

#define AT4(DST, ROW, V) \
  atomicAdd(&(DST)[(ROW) * 32 + g2 * 4 + 0], (V).x); \
  atomicAdd(&(DST)[(ROW) * 32 + g2 * 4 + 1], (V).y); \
  atomicAdd(&(DST)[(ROW) * 32 + g2 * 4 + 2], (V).z); \
  atomicAdd(&(DST)[(ROW) * 32 + g2 * 4 + 3], (V).w);

#define MERGE_GRP(P, COMP) { \
  float* dst_ = m2s + ((size_t)slot * 32 + (COMP)) * 1024; \
  AT4(dst_, g1 * 4 + 0, P##r0) \
  AT4(dst_, g1 * 4 + 1, P##r1) \
  AT4(dst_, g1 * 4 + 2, P##r2) \
  AT4(dst_, g1 * 4 + 3, P##r3) \
  if (g1 == 0) { \
    float* md_ = muss + ((size_t)slot * 32 + (COMP)) * 32 + g2 * 4; \
    atomicAdd(md_ + 0, P##m.x); atomicAdd(md_ + 1, P##m.y); \
    atomicAdd(md_ + 2, P##m.z); atomicAdd(md_ + 3, P##m.w); \
  } \
  if (l == 0) atomicAdd(&dns[slot * 32 + (COMP)], P##d); }

// Streams X sequentially (double-buffered global_load_lds, counted vmcnt(6)).
// 8 waves/block; per 256-point chunk build per-cluster lists from staged z,
// then each wave accumulates its 2 clusters (lane = 4x4 (d1,d2) tile).
// Accumulators are NAMED float4/float scalars (macros above): R3-R5 showed the
// compiler leaves C arrays here in scratch (258MB HBM RMW traffic, VALU 9%)
// regardless of launch_bounds; named scalars cannot be runtime-indexed.
__global__ __launch_bounds__(512, 2) void mstep_k(
    const float* __restrict__ X, const unsigned char* __restrict__ zb,
    const float* __restrict__ wpairf,
    float* __restrict__ m2s, float* __restrict__ muss, float* __restrict__ dns,
    int n)
{
  __shared__ float xls[2][CHUNK * 32];          // 64 KB
  __shared__ float wls[2][CHUNK * 2];           // 4 KB
  __shared__ unsigned char zls[2][CHUNK];       // 512 B
  __shared__ unsigned char list[2][16][CHUNK];  // 8 KB
  __shared__ int lcnt[2][16];

  const int t = threadIdx.x;
  const int wv = t >> 6;      // 0..7
  const int l = t & 63;
  const int g1 = l >> 3;
  const int g2 = l & 7;
  const int bs = blockIdx.x * PPB;
  const int be = min(bs + PPB, n);
  const int nsc = (be - bs + CHUNK - 1) / CHUNK;
  const int slot = blockIdx.x & (NSLOT - 1);

  DECL_GRP(g00)   // cluster wv*2+0, sub 0
  DECL_GRP(g01)   // cluster wv*2+0, sub 1
  DECL_GRP(g10)   // cluster wv*2+1, sub 0
  DECL_GRP(g11)   // cluster wv*2+1, sub 1

  auto stage = [&](int i) {
    const int c0 = bs + i * CHUNK;
    const int buf = i & 1;
    // X rows: wave wv covers rows [wv*32, wv*32+32); 4 instr x 1KB contiguous
#pragma unroll
    for (int q = 0; q < 4; ++q) {
      int gi = c0 + wv * 32 + q * 8 + g1;
      if (gi > n - 1) gi = n - 1;
      gld_lds16(X + (size_t)gi * 32 + (g2 << 2), &xls[buf][(wv * 32 + q * 8) * 32]);
    }
    // w pairs: 512 floats; wave wv covers [wv*64, +64) via 1 instr
    {
      long gfi = (long)c0 * 2 + wv * 64 + l;
      if (gfi > 2L * n - 1) gfi = 2L * n - 1;
      gld_lds4(wpairf + gfi, &wls[buf][wv * 64]);
    }
    // z bytes: 256 B; all 8 waves issue identical load (benign dup) to keep
    // per-wave vmcnt uniform (6 per stage)
    gld_lds4(zb + c0 + 4 * l, &zls[buf][0]);
  };

  stage(0);
  if (t < 16) lcnt[0][t] = 0;

  for (int i = 0; i < nsc; ++i) {
    const int buf = i & 1;
    if (i + 1 < nsc) { stage(i + 1); WAITVM6; } else { WAITVM0; }
    WAITLGKM;
    BAR;  // A: stage(i) data + lcnt[buf] zero visible

    int rem = be - (bs + i * CHUNK); if (rem > CHUNK) rem = CHUNK;
    if (t < rem) {
      int zv = zls[buf][t];
      int pos = atomicAdd(&lcnt[buf][zv], 1);
      list[buf][zv][pos] = (unsigned char)t;
    }
    if (t < 16) lcnt[buf ^ 1][t] = 0;
    WAITLGKM;
    BAR;  // B: lists ready

    const float* xb = xls[buf];
    const float* wb = wls[buf];
    CLUSTER_LOOP(wv * 2 + 0, g00, g01)
    CLUSTER_LOOP(wv * 2 + 1, g10, g11)
    WAITLGKM;
    BAR;  // C: all reads of buf complete before it is restaged
  }

  // merge: slot-spread global atomics (each wave owns distinct comps)
  MERGE_GRP(g00, wv * 4 + 0)
  MERGE_GRP(g01, wv * 4 + 1)
  MERGE_GRP(g10, wv * 4 + 2)
  MERGE_GRP(g11, wv * 4 + 3)
}

__global__ __launch_bounds__(256) void finalize_k(
    const float* __restrict__ pig, const float* __restrict__ dns,
    const float* __restrict__ muss, const float* __restrict__ m2s,
    float* __restrict__ out, int n)
{
  const int c = blockIdx.x;   // component 0..31
  const int t = threadIdx.x;
  __shared__ float mu[32];
  float dsum = 0.f;
#pragma unroll
  for (int s = 0; s < NSLOT; ++s) dsum += dns[s * 32 + c];
  float safe = fmaxf(dsum, 1e-10f);
  if (t < 32) {
    float m = 0.f;
#pragma unroll
    for (int s = 0; s < NSLOT; ++s) m += muss[((size_t)s * 32 + c) * 32 + t];
    m /= safe;
    mu[t] = m;
    out[32 + c * 32 + t] = m;                       // mus
  }
  if (c == 0 && t < 32) out[t] = pig[t] / (float)n; // pi
  __syncthreads();
#pragma unroll
  for (int q = 0; q < 4; ++q) {
    int e = t * 4 + q;
    float m2 = 0.f;
#pragma unroll
    for (int s = 0; s < NSLOT; ++s) m2 += m2s[((size_t)s * 32 + c) * 1024 + e];
    out[32 + 1024 + c * 1024 + e] = m2 / safe - mu[e >> 5] * mu[e & 31];
  }
}

extern "C" void kernel_launch(void* const* d_in, const int* in_sizes, int n_in,
                              void* d_out, int out_size, void* d_ws, size_t ws_size,
                              hipStream_t stream) {
  const float* X  = (const float*)d_in[0];
  const float* r  = (const float*)d_in[1];
  const float* ri = (const float*)d_in[2];
  float* out = (float*)d_out;
  const int n = in_sizes[0] / 32;

  // ws layout (floats unless noted)
  float* wpair = (float*)d_ws;                         // 2n
  float* m2s   = wpair + 2 * (size_t)n;                // NSLOT*32*1024
  float* muss  = m2s + (size_t)NSLOT * 32 * 1024;      // NSLOT*32*32
  float* dns   = muss + NSLOT * 32 * 32;               // NSLOT*32
  float* pig   = dns + NSLOT * 32;                     // 32
  unsigned char* zbuf = (unsigned char*)(pig + 32);    // n + 256 pad

  const int zero_words = NSLOT * 32 * 1024 + NSLOT * 32 * 32 + NSLOT * 32 + 32;
  zero_k<<<(zero_words + 255) / 256, 256, 0, stream>>>(m2s, zero_words);
  prep_k<<<1024, 256, 0, stream>>>(r, ri, zbuf, wpair, pig, n);
  const int grid_m = (n + PPB - 1) / PPB;
  mstep_k<<<grid_m, 512, 0, stream>>>(X, zbuf, wpair, m2s, muss, dns, n);
  finalize_k<<<32, 256, 0, stream>>>(pig, dns, muss, m2s, out, n);
}

// Round 7
// 229.682 us; speedup vs baseline: 1.6442x; 1.6442x over previous
//
#include <hip/hip_runtime.h>

#define AS1 __attribute__((address_space(1)))
#define AS3 __attribute__((address_space(3)))
#define CHUNK 256

__device__ __forceinline__ void gld_lds16(const float* g, float* l) {
  __builtin_amdgcn_global_load_lds((const AS1 void*)g, (AS3 void*)l, 16, 0, 0);
}
__device__ __forceinline__ void gld_lds4(const void* g, void* l) {
  __builtin_amdgcn_global_load_lds((const AS1 void*)g, (AS3 void*)l, 4, 0, 0);
}

#define WAITVM6  do { asm volatile("s_waitcnt vmcnt(6)" ::: "memory"); __builtin_amdgcn_sched_barrier(0); } while (0)
#define WAITVM0  do { asm volatile("s_waitcnt vmcnt(0)" ::: "memory"); __builtin_amdgcn_sched_barrier(0); } while (0)
#define WAITLGKM do { asm volatile("s_waitcnt lgkmcnt(0)" ::: "memory"); __builtin_amdgcn_sched_barrier(0); } while (0)
#define BAR __builtin_amdgcn_s_barrier()

__global__ void zero_k(float* __restrict__ p, int n) {
  int i = blockIdx.x * blockDim.x + threadIdx.x;
  if (i < n) p[i] = 0.f;
}

// Streams r + ri once. Outputs: zb (u8 argmax), wpair (float2 gated resp),
// pig (global partial sums of ri columns).
__global__ __launch_bounds__(256) void prep_k(
    const float* __restrict__ r, const float* __restrict__ ri,
    unsigned char* __restrict__ zb, float* __restrict__ wpairf,
    float* __restrict__ pig, int n)
{
  __shared__ float lpi[256][33];
  float acc[32];
#pragma unroll
  for (int c = 0; c < 32; ++c) acc[c] = 0.f;

  for (int i = blockIdx.x * blockDim.x + threadIdx.x; i < n;
       i += gridDim.x * blockDim.x) {
    const float4* rr = (const float4*)(r + (size_t)i * 16);
    float4 a0 = rr[0], a1 = rr[1], a2 = rr[2], a3 = rr[3];
    float best = a0.x; int z = 0;
#define CHK(v, c) if ((v) > best) { best = (v); z = (c); }
    CHK(a0.y,1) CHK(a0.z,2) CHK(a0.w,3)
    CHK(a1.x,4) CHK(a1.y,5) CHK(a1.z,6) CHK(a1.w,7)
    CHK(a2.x,8) CHK(a2.y,9) CHK(a2.z,10) CHK(a2.w,11)
    CHK(a3.x,12) CHK(a3.y,13) CHK(a3.z,14) CHK(a3.w,15)
#undef CHK
    const float4* qq = (const float4*)(ri + (size_t)i * 32);
    float4 v0 = qq[0], v1 = qq[1], v2 = qq[2], v3 = qq[3];
    float4 v4 = qq[4], v5 = qq[5], v6 = qq[6], v7 = qq[7];
    acc[0]+=v0.x; acc[1]+=v0.y; acc[2]+=v0.z; acc[3]+=v0.w;
    acc[4]+=v1.x; acc[5]+=v1.y; acc[6]+=v1.z; acc[7]+=v1.w;
    acc[8]+=v2.x; acc[9]+=v2.y; acc[10]+=v2.z; acc[11]+=v2.w;
    acc[12]+=v3.x; acc[13]+=v3.y; acc[14]+=v3.z; acc[15]+=v3.w;
    acc[16]+=v4.x; acc[17]+=v4.y; acc[18]+=v4.z; acc[19]+=v4.w;
    acc[20]+=v5.x; acc[21]+=v5.y; acc[22]+=v5.z; acc[23]+=v5.w;
    acc[24]+=v6.x; acc[25]+=v6.y; acc[26]+=v6.z; acc[27]+=v6.w;
    acc[28]+=v7.x; acc[29]+=v7.y; acc[30]+=v7.z; acc[31]+=v7.w;
    // select ri[2z], ri[2z+1] from registers (cndmask tree)
    int q = z >> 1;
    float4 sel = q < 4 ? (q < 2 ? (q == 0 ? v0 : v1) : (q == 2 ? v2 : v3))
                       : (q < 6 ? (q == 4 ? v4 : v5) : (q == 6 ? v6 : v7));
    float w0 = (z & 1) ? sel.z : sel.x;
    float w1 = (z & 1) ? sel.w : sel.y;
    zb[i] = (unsigned char)z;
    *(float2*)&wpairf[(size_t)i * 2] = make_float2(w0, w1);
  }

#pragma unroll
  for (int c = 0; c < 32; ++c) lpi[threadIdx.x][c] = acc[c];
  __syncthreads();
  if (threadIdx.x < 32) {
    float s = 0.f;
    for (int t = 0; t < 256; ++t) s += lpi[t][threadIdx.x];
    atomicAdd(&pig[threadIdx.x], s);
  }
}

// ---- named-scalar accumulator groups (no arrays -> no scratch) ----
#define DECL_GRP(P) \
  float4 P##r0 = make_float4(0,0,0,0), P##r1 = make_float4(0,0,0,0), \
         P##r2 = make_float4(0,0,0,0), P##r3 = make_float4(0,0,0,0), \
         P##m  = make_float4(0,0,0,0); \
  float P##d = 0.f;

#define FMA4(ACC, S, V) \
  ACC.x += (S) * (V).x; ACC.y += (S) * (V).y; \
  ACC.z += (S) * (V).z; ACC.w += (S) * (V).w;

#define UPD_GRP(P, W, X1, X2) { float s_; \
  s_ = (W) * (X1).x; FMA4(P##r0, s_, X2); \
  s_ = (W) * (X1).y; FMA4(P##r1, s_, X2); \
  s_ = (W) * (X1).z; FMA4(P##r2, s_, X2); \
  s_ = (W) * (X1).w; FMA4(P##r3, s_, X2); \
  FMA4(P##m, W, X2); \
  P##d += (W); }

#define CLUSTER_LOOP(KK, A, B) { \
  const int cnt_ = lcnt[buf][KK]; \
  const unsigned char* lk_ = list[buf][KK]; \
  _Pragma("unroll 2") \
  for (int j = 0; j < cnt_; ++j) { \
    int p_ = lk_[j]; \
    float2 wp_ = *(const float2*)&wb[p_ * 2]; \
    float4 x1_ = *(const float4*)&xb[p_ * 32 + g1 * 4]; \
    float4 x2_ = *(const float4*)&xb[p_ * 32 + g2 * 4]; \
    UPD_GRP(A, wp_.x, x1_, x2_); \
    UPD_GRP(B, wp_.y, x1_, x2_); \
  } }

// Plain cached float4 stores to this block's partial slice. NO global atomics:
// R3-R6 showed per-lane scattered fp32 atomicAdd generates 64B uncached line
// traffic per touch (258MB @ ~750GB/s = the whole 345us kernel time).
#define STORE_GRP(P, COMP) { \
  float* dst_ = m2p + ((size_t)blockIdx.x * 32 + (COMP)) * 1024; \
  *(float4*)&dst_[(g1 * 4 + 0) * 32 + g2 * 4] = P##r0; \
  *(float4*)&dst_[(g1 * 4 + 1) * 32 + g2 * 4] = P##r1; \
  *(float4*)&dst_[(g1 * 4 + 2) * 32 + g2 * 4] = P##r2; \
  *(float4*)&dst_[(g1 * 4 + 3) * 32 + g2 * 4] = P##r3; \
  if (g1 == 0) \
    *(float4*)&musp[((size_t)blockIdx.x * 32 + (COMP)) * 32 + g2 * 4] = P##m; \
  if (l == 0) dnp[blockIdx.x * 32 + (COMP)] = P##d; }

// Streams X sequentially (double-buffered global_load_lds, counted vmcnt(6)),
// grid-stride over 256-point chunks. 8 waves/block; per chunk build
// per-cluster lists from staged z, each wave accumulates its 2 clusters
// (lane = 4x4 (d1,d2) tile), then writes per-block partials (no atomics).
__global__ __launch_bounds__(512, 2) void mstep_k(
    const float* __restrict__ X, const unsigned char* __restrict__ zb,
    const float* __restrict__ wpairf,
    float* __restrict__ m2p, float* __restrict__ musp, float* __restrict__ dnp,
    int n, int nchunks)
{
  __shared__ float xls[2][CHUNK * 32];          // 64 KB
  __shared__ float wls[2][CHUNK * 2];           // 4 KB
  __shared__ unsigned char zls[2][CHUNK];       // 512 B
  __shared__ unsigned char list[2][16][CHUNK];  // 8 KB
  __shared__ int lcnt[2][16];

  const int t = threadIdx.x;
  const int wv = t >> 6;      // 0..7
  const int l = t & 63;
  const int g1 = l >> 3;
  const int g2 = l & 7;

  DECL_GRP(g00)   // cluster wv*2+0, sub 0
  DECL_GRP(g01)   // cluster wv*2+0, sub 1
  DECL_GRP(g10)   // cluster wv*2+1, sub 0
  DECL_GRP(g11)   // cluster wv*2+1, sub 1

  auto stage = [&](int ch, int buf) {
    const int c0 = ch * CHUNK;
    // X rows: wave wv covers rows [wv*32, wv*32+32); 4 instr x 1KB contiguous
#pragma unroll
    for (int q = 0; q < 4; ++q) {
      int gi = c0 + wv * 32 + q * 8 + g1;
      if (gi > n - 1) gi = n - 1;
      gld_lds16(X + (size_t)gi * 32 + (g2 << 2), &xls[buf][(wv * 32 + q * 8) * 32]);
    }
    // w pairs: 512 floats; wave wv covers [wv*64, +64) via 1 instr
    {
      long gfi = (long)c0 * 2 + wv * 64 + l;
      if (gfi > 2L * n - 1) gfi = 2L * n - 1;
      gld_lds4(wpairf + gfi, &wls[buf][wv * 64]);
    }
    // z bytes: 256 B; all 8 waves issue identical load (benign dup) to keep
    // per-wave vmcnt uniform (6 per stage)
    gld_lds4(zb + c0 + 4 * l, &zls[buf][0]);
  };

  int ch = blockIdx.x;
  if (ch < nchunks) stage(ch, 0);
  if (t < 16) lcnt[0][t] = 0;

  for (int i = 0; ch < nchunks; ++i, ch += gridDim.x) {
    const int buf = i & 1;
    const int nch = ch + gridDim.x;
    if (nch < nchunks) { stage(nch, buf ^ 1); WAITVM6; } else { WAITVM0; }
    WAITLGKM;
    BAR;  // A: stage data + lcnt[buf] zeros visible

    int rem = n - ch * CHUNK; if (rem > CHUNK) rem = CHUNK;
    if (t < rem) {
      int zv = zls[buf][t];
      int pos = atomicAdd(&lcnt[buf][zv], 1);
      list[buf][zv][pos] = (unsigned char)t;
    }
    if (t < 16) lcnt[buf ^ 1][t] = 0;
    WAITLGKM;
    BAR;  // B: lists ready

    const float* xb = xls[buf];
    const float* wb = wls[buf];
    CLUSTER_LOOP(wv * 2 + 0, g00, g01)
    CLUSTER_LOOP(wv * 2 + 1, g10, g11)
    WAITLGKM;
    BAR;  // C: all reads of buf complete before it is restaged
  }

  STORE_GRP(g00, wv * 4 + 0)
  STORE_GRP(g01, wv * 4 + 1)
  STORE_GRP(g10, wv * 4 + 2)
  STORE_GRP(g11, wv * 4 + 3)
}

// Reduce NB per-block partials. 32 blocks (one per component), 256 threads.
__global__ __launch_bounds__(256) void finalize_k(
    const float* __restrict__ pig, const float* __restrict__ dnp,
    const float* __restrict__ musp, const float* __restrict__ m2p,
    float* __restrict__ out, int n, int NB)
{
  const int c = blockIdx.x;   // component 0..31
  const int t = threadIdx.x;
  __shared__ float mu[32];

  // denom: all threads redundantly sum NB scalars (broadcast loads)
  float dsum = 0.f;
#pragma unroll 4
  for (int b = 0; b < NB; ++b) dsum += dnp[b * 32 + c];
  float safe = fmaxf(dsum, 1e-10f);

  if (t < 32) {
    float m = 0.f;
#pragma unroll 4
    for (int b = 0; b < NB; ++b) m += musp[((size_t)b * 32 + c) * 32 + t];
    m /= safe;
    mu[t] = m;
    out[32 + c * 32 + t] = m;                       // mus
  }
  if (c == 0 && t < 32) out[t] = pig[t] / (float)n; // pi
  __syncthreads();

  // m2: thread t owns floats [t*4, t*4+4) of the 1024-elem matrix
  float4 acc = make_float4(0.f, 0.f, 0.f, 0.f);
#pragma unroll 4
  for (int b = 0; b < NB; ++b) {
    float4 v = *(const float4*)&m2p[((size_t)b * 32 + c) * 1024 + t * 4];
    acc.x += v.x; acc.y += v.y; acc.z += v.z; acc.w += v.w;
  }
  const int d1 = t >> 3;            // (t*4)>>5
  const int c0 = (t * 4) & 31;
  float mud1 = mu[d1];
  float4 cov;
  cov.x = acc.x / safe - mud1 * mu[c0 + 0];
  cov.y = acc.y / safe - mud1 * mu[c0 + 1];
  cov.z = acc.z / safe - mud1 * mu[c0 + 2];
  cov.w = acc.w / safe - mud1 * mu[c0 + 3];
  *(float4*)&out[32 + 1024 + c * 1024 + t * 4] = cov;  // covs
}

extern "C" void kernel_launch(void* const* d_in, const int* in_sizes, int n_in,
                              void* d_out, int out_size, void* d_ws, size_t ws_size,
                              hipStream_t stream) {
  const float* X  = (const float*)d_in[0];
  const float* r  = (const float*)d_in[1];
  const float* ri = (const float*)d_in[2];
  float* out = (float*)d_out;
  const int n = in_sizes[0] / 32;
  const int nchunks = (n + CHUNK - 1) / CHUNK;

  // NB (mstep blocks = partial slots) sized from ws: per-block partial bytes
  // = 32 comps * (1024 m2 + 32 mus + 1 dn) * 4B = 135,296 B.
  const size_t fixed_b = (size_t)(2 * n + 32) * 4 + (size_t)(n + 512) + 4096;
  const size_t per_nb = 32ull * (1024 + 32 + 1) * 4;
  int NB = 512;
  if (ws_size < fixed_b + (size_t)NB * per_nb) {
    size_t avail = ws_size > fixed_b ? (ws_size - fixed_b) / per_nb : 8;
    NB = (int)(avail < 8 ? 8 : avail);
    if (NB > 512) NB = 512;
  }

  // ws layout: [m2p | musp | dnp | wpair | pig | zbuf]
  float* m2p   = (float*)d_ws;                          // NB*32*1024
  float* musp  = m2p + (size_t)NB * 32 * 1024;          // NB*32*32
  float* dnp   = musp + (size_t)NB * 32 * 32;           // NB*32
  float* wpair = dnp + (size_t)NB * 32;                 // 2n
  float* pig   = wpair + 2 * (size_t)n;                 // 32
  unsigned char* zbuf = (unsigned char*)(pig + 32);     // n + pad

  zero_k<<<1, 32, 0, stream>>>(pig, 32);
  prep_k<<<1024, 256, 0, stream>>>(r, ri, zbuf, wpair, pig, n);
  mstep_k<<<NB, 512, 0, stream>>>(X, zbuf, wpair, m2p, musp, dnp, n, nchunks);
  finalize_k<<<32, 256, 0, stream>>>(pig, dnp, musp, m2p, out, n, NB);
}

// Round 8
// 127.191 us; speedup vs baseline: 2.9692x; 1.8058x over previous
//
#include <hip/hip_runtime.h>

#define AS1 __attribute__((address_space(1)))
#define AS3 __attribute__((address_space(3)))
#define CHUNK 256

__device__ __forceinline__ void gld_lds16(const float* g, float* l) {
  __builtin_amdgcn_global_load_lds((const AS1 void*)g, (AS3 void*)l, 16, 0, 0);
}
__device__ __forceinline__ void gld_lds4(const void* g, void* l) {
  __builtin_amdgcn_global_load_lds((const AS1 void*)g, (AS3 void*)l, 4, 0, 0);
}

#define WAITVM6  do { asm volatile("s_waitcnt vmcnt(6)" ::: "memory"); __builtin_amdgcn_sched_barrier(0); } while (0)
#define WAITVM0  do { asm volatile("s_waitcnt vmcnt(0)" ::: "memory"); __builtin_amdgcn_sched_barrier(0); } while (0)
#define WAITLGKM do { asm volatile("s_waitcnt lgkmcnt(0)" ::: "memory"); __builtin_amdgcn_sched_barrier(0); } while (0)
#define BAR __builtin_amdgcn_s_barrier()

__global__ void zero_k(float* __restrict__ p, int n) {
  int i = blockIdx.x * blockDim.x + threadIdx.x;
  if (i < n) p[i] = 0.f;
}

// Streams r + ri once. Outputs: zb (u8 argmax), wpair (float2 gated resp),
// pig (global partial sums of ri columns).
__global__ __launch_bounds__(256) void prep_k(
    const float* __restrict__ r, const float* __restrict__ ri,
    unsigned char* __restrict__ zb, float* __restrict__ wpairf,
    float* __restrict__ pig, int n)
{
  __shared__ float lpi[256][33];
  float acc[32];
#pragma unroll
  for (int c = 0; c < 32; ++c) acc[c] = 0.f;

  for (int i = blockIdx.x * blockDim.x + threadIdx.x; i < n;
       i += gridDim.x * blockDim.x) {
    const float4* rr = (const float4*)(r + (size_t)i * 16);
    float4 a0 = rr[0], a1 = rr[1], a2 = rr[2], a3 = rr[3];
    float best = a0.x; int z = 0;
#define CHK(v, c) if ((v) > best) { best = (v); z = (c); }
    CHK(a0.y,1) CHK(a0.z,2) CHK(a0.w,3)
    CHK(a1.x,4) CHK(a1.y,5) CHK(a1.z,6) CHK(a1.w,7)
    CHK(a2.x,8) CHK(a2.y,9) CHK(a2.z,10) CHK(a2.w,11)
    CHK(a3.x,12) CHK(a3.y,13) CHK(a3.z,14) CHK(a3.w,15)
#undef CHK
    const float4* qq = (const float4*)(ri + (size_t)i * 32);
    float4 v0 = qq[0], v1 = qq[1], v2 = qq[2], v3 = qq[3];
    float4 v4 = qq[4], v5 = qq[5], v6 = qq[6], v7 = qq[7];
    acc[0]+=v0.x; acc[1]+=v0.y; acc[2]+=v0.z; acc[3]+=v0.w;
    acc[4]+=v1.x; acc[5]+=v1.y; acc[6]+=v1.z; acc[7]+=v1.w;
    acc[8]+=v2.x; acc[9]+=v2.y; acc[10]+=v2.z; acc[11]+=v2.w;
    acc[12]+=v3.x; acc[13]+=v3.y; acc[14]+=v3.z; acc[15]+=v3.w;
    acc[16]+=v4.x; acc[17]+=v4.y; acc[18]+=v4.z; acc[19]+=v4.w;
    acc[20]+=v5.x; acc[21]+=v5.y; acc[22]+=v5.z; acc[23]+=v5.w;
    acc[24]+=v6.x; acc[25]+=v6.y; acc[26]+=v6.z; acc[27]+=v6.w;
    acc[28]+=v7.x; acc[29]+=v7.y; acc[30]+=v7.z; acc[31]+=v7.w;
    // select ri[2z], ri[2z+1] from registers (cndmask tree)
    int q = z >> 1;
    float4 sel = q < 4 ? (q < 2 ? (q == 0 ? v0 : v1) : (q == 2 ? v2 : v3))
                       : (q < 6 ? (q == 4 ? v4 : v5) : (q == 6 ? v6 : v7));
    float w0 = (z & 1) ? sel.z : sel.x;
    float w1 = (z & 1) ? sel.w : sel.y;
    zb[i] = (unsigned char)z;
    *(float2*)&wpairf[(size_t)i * 2] = make_float2(w0, w1);
  }

#pragma unroll
  for (int c = 0; c < 32; ++c) lpi[threadIdx.x][c] = acc[c];
  __syncthreads();
  if (threadIdx.x < 32) {
    float s = 0.f;
    for (int t = 0; t < 256; ++t) s += lpi[t][threadIdx.x];
    atomicAdd(&pig[threadIdx.x], s);
  }
}

// ---- named-scalar accumulator groups (no arrays -> no scratch) ----
#define DECL_GRP(P) \
  float4 P##r0 = make_float4(0,0,0,0), P##r1 = make_float4(0,0,0,0), \
         P##r2 = make_float4(0,0,0,0), P##r3 = make_float4(0,0,0,0), \
         P##m  = make_float4(0,0,0,0); \
  float P##d = 0.f;

#define FMA4(ACC, S, V) \
  ACC.x += (S) * (V).x; ACC.y += (S) * (V).y; \
  ACC.z += (S) * (V).z; ACC.w += (S) * (V).w;

#define UPD_GRP(P, W, X1, X2) { float s_; \
  s_ = (W) * (X1).x; FMA4(P##r0, s_, X2); \
  s_ = (W) * (X1).y; FMA4(P##r1, s_, X2); \
  s_ = (W) * (X1).z; FMA4(P##r2, s_, X2); \
  s_ = (W) * (X1).w; FMA4(P##r3, s_, X2); \
  FMA4(P##m, W, X2); \
  P##d += (W); }

#define CLUSTER_LOOP(KK, A, B) { \
  const int cnt_ = lcnt[buf][KK]; \
  const unsigned char* lk_ = list[buf][KK]; \
  _Pragma("unroll 2") \
  for (int j = 0; j < cnt_; ++j) { \
    int p_ = lk_[j]; \
    float2 wp_ = *(const float2*)&wb[p_ * 2]; \
    float4 x1_ = *(const float4*)&xb[p_ * 32 + g1 * 4]; \
    float4 x2_ = *(const float4*)&xb[p_ * 32 + g2 * 4]; \
    UPD_GRP(A, wp_.x, x1_, x2_); \
    UPD_GRP(B, wp_.y, x1_, x2_); \
  } }

// Plain cached float4 stores to this block's partial slice. NO global atomics:
// R3-R6 showed per-lane scattered fp32 atomicAdd generates 64B uncached line
// traffic per touch (258MB @ ~750GB/s = the whole 345us kernel time).
#define STORE_GRP(P, COMP) { \
  float* dst_ = m2p + ((size_t)blockIdx.x * 32 + (COMP)) * 1024; \
  *(float4*)&dst_[(g1 * 4 + 0) * 32 + g2 * 4] = P##r0; \
  *(float4*)&dst_[(g1 * 4 + 1) * 32 + g2 * 4] = P##r1; \
  *(float4*)&dst_[(g1 * 4 + 2) * 32 + g2 * 4] = P##r2; \
  *(float4*)&dst_[(g1 * 4 + 3) * 32 + g2 * 4] = P##r3; \
  if (g1 == 0) \
    *(float4*)&musp[((size_t)blockIdx.x * 32 + (COMP)) * 32 + g2 * 4] = P##m; \
  if (l == 0) dnp[blockIdx.x * 32 + (COMP)] = P##d; }

// Streams X sequentially (double-buffered global_load_lds, counted vmcnt(6)),
// grid-stride over 256-point chunks. 8 waves/block; per chunk build
// per-cluster lists from staged z, each wave accumulates its 2 clusters
// (lane = 4x4 (d1,d2) tile), then writes per-block partials (no atomics).
__global__ __launch_bounds__(512, 2) void mstep_k(
    const float* __restrict__ X, const unsigned char* __restrict__ zb,
    const float* __restrict__ wpairf,
    float* __restrict__ m2p, float* __restrict__ musp, float* __restrict__ dnp,
    int n, int nchunks)
{
  __shared__ float xls[2][CHUNK * 32];          // 64 KB
  __shared__ float wls[2][CHUNK * 2];           // 4 KB
  __shared__ unsigned char zls[2][CHUNK];       // 512 B
  __shared__ unsigned char list[2][16][CHUNK];  // 8 KB
  __shared__ int lcnt[2][16];

  const int t = threadIdx.x;
  const int wv = t >> 6;      // 0..7
  const int l = t & 63;
  const int g1 = l >> 3;
  const int g2 = l & 7;

  DECL_GRP(g00)   // cluster wv*2+0, sub 0
  DECL_GRP(g01)   // cluster wv*2+0, sub 1
  DECL_GRP(g10)   // cluster wv*2+1, sub 0
  DECL_GRP(g11)   // cluster wv*2+1, sub 1

  auto stage = [&](int ch, int buf) {
    const int c0 = ch * CHUNK;
    // X rows: wave wv covers rows [wv*32, wv*32+32); 4 instr x 1KB contiguous
#pragma unroll
    for (int q = 0; q < 4; ++q) {
      int gi = c0 + wv * 32 + q * 8 + g1;
      if (gi > n - 1) gi = n - 1;
      gld_lds16(X + (size_t)gi * 32 + (g2 << 2), &xls[buf][(wv * 32 + q * 8) * 32]);
    }
    // w pairs: 512 floats; wave wv covers [wv*64, +64) via 1 instr
    {
      long gfi = (long)c0 * 2 + wv * 64 + l;
      if (gfi > 2L * n - 1) gfi = 2L * n - 1;
      gld_lds4(wpairf + gfi, &wls[buf][wv * 64]);
    }
    // z bytes: 256 B; all 8 waves issue identical load (benign dup) to keep
    // per-wave vmcnt uniform (6 per stage)
    gld_lds4(zb + c0 + 4 * l, &zls[buf][0]);
  };

  int ch = blockIdx.x;
  if (ch < nchunks) stage(ch, 0);
  if (t < 16) lcnt[0][t] = 0;

  for (int i = 0; ch < nchunks; ++i, ch += gridDim.x) {
    const int buf = i & 1;
    const int nch = ch + gridDim.x;
    if (nch < nchunks) { stage(nch, buf ^ 1); WAITVM6; } else { WAITVM0; }
    WAITLGKM;
    BAR;  // A: stage data + lcnt[buf] zeros visible

    int rem = n - ch * CHUNK; if (rem > CHUNK) rem = CHUNK;
    if (t < rem) {
      int zv = zls[buf][t];
      int pos = atomicAdd(&lcnt[buf][zv], 1);
      list[buf][zv][pos] = (unsigned char)t;
    }
    if (t < 16) lcnt[buf ^ 1][t] = 0;
    WAITLGKM;
    BAR;  // B: lists ready

    const float* xb = xls[buf];
    const float* wb = wls[buf];
    CLUSTER_LOOP(wv * 2 + 0, g00, g01)
    CLUSTER_LOOP(wv * 2 + 1, g10, g11)
    WAITLGKM;
    BAR;  // C: all reads of buf complete before it is restaged
  }

  STORE_GRP(g00, wv * 4 + 0)
  STORE_GRP(g01, wv * 4 + 1)
  STORE_GRP(g10, wv * 4 + 2)
  STORE_GRP(g11, wv * 4 + 3)
}

// Parallel partial-reduction. Treats m2p as a [NB][32768] matrix (b-major,
// contiguous per b) and column-sums it with 256 blocks; musp ([NB][1024]) with
// 8 blocks; dnp ([NB][32]) with 1 block. Each thread: 32-col group, 8-way
// row split -> NB/8 independent coalesced float4 loads (MLP), LDS 8->1.
__global__ __launch_bounds__(256) void reduce_k(
    const float* __restrict__ m2p, const float* __restrict__ musp,
    const float* __restrict__ dnp,
    float* __restrict__ m2r, float* __restrict__ musr, float* __restrict__ dnr,
    int NB)
{
  __shared__ float4 red[256];
  const int t = threadIdx.x;
  const int bid = blockIdx.x;

  if (bid < 264) {
    const float* in; float* outp; int rs, colbase;
    if (bid < 256) { in = m2p;  outp = m2r;  rs = 32768; colbase = bid * 32; }
    else           { in = musp; outp = musr; rs = 1024;  colbase = (bid - 256) * 32; }
    const int col = colbase + (t & 31);
    float4 a = make_float4(0.f, 0.f, 0.f, 0.f);
#pragma unroll 4
    for (int b = t >> 5; b < NB; b += 8) {
      float4 v = *(const float4*)&in[(size_t)b * rs + col * 4];
      a.x += v.x; a.y += v.y; a.z += v.z; a.w += v.w;
    }
    red[t] = a;
    __syncthreads();
    if (t < 32) {
      float4 s = red[t];
#pragma unroll
      for (int q = 1; q < 8; ++q) {
        float4 v = red[t + q * 32];
        s.x += v.x; s.y += v.y; s.z += v.z; s.w += v.w;
      }
      *(float4*)&outp[col * 4] = s;
    }
  } else {
    // dn: [NB][32] column-sum
    float a = 0.f;
    const int c = t & 31;
#pragma unroll 4
    for (int b = t >> 5; b < NB; b += 8) a += dnp[b * 32 + c];
    __shared__ float redf[256];
    redf[t] = a;
    __syncthreads();
    if (t < 32) {
      float s = redf[t];
#pragma unroll
      for (int q = 1; q < 8; ++q) s += redf[t + q * 32];
      dnr[c] = s;
    }
  }
}

// Final epilogue: reads only the reduced 132KB.
__global__ __launch_bounds__(256) void finalize_k(
    const float* __restrict__ pig, const float* __restrict__ dnr,
    const float* __restrict__ musr, const float* __restrict__ m2r,
    float* __restrict__ out, int n)
{
  const int c = blockIdx.x;   // component 0..31
  const int t = threadIdx.x;
  __shared__ float mu[32];
  float safe = fmaxf(dnr[c], 1e-10f);
  if (t < 32) {
    float m = musr[c * 32 + t] / safe;
    mu[t] = m;
    out[32 + c * 32 + t] = m;                       // mus
  }
  if (c == 0 && t < 32) out[t] = pig[t] / (float)n; // pi
  __syncthreads();
  float4 acc = *(const float4*)&m2r[c * 1024 + t * 4];
  const int d1 = t >> 3;            // (t*4)>>5
  const int c0 = (t * 4) & 31;
  float mud1 = mu[d1];
  float4 cov;
  cov.x = acc.x / safe - mud1 * mu[c0 + 0];
  cov.y = acc.y / safe - mud1 * mu[c0 + 1];
  cov.z = acc.z / safe - mud1 * mu[c0 + 2];
  cov.w = acc.w / safe - mud1 * mu[c0 + 3];
  *(float4*)&out[32 + 1024 + c * 1024 + t * 4] = cov;  // covs
}

extern "C" void kernel_launch(void* const* d_in, const int* in_sizes, int n_in,
                              void* d_out, int out_size, void* d_ws, size_t ws_size,
                              hipStream_t stream) {
  const float* X  = (const float*)d_in[0];
  const float* r  = (const float*)d_in[1];
  const float* ri = (const float*)d_in[2];
  float* out = (float*)d_out;
  const int n = in_sizes[0] / 32;
  const int nchunks = (n + CHUNK - 1) / CHUNK;

  // NB (mstep blocks = partial slots) sized from ws: per-block partial bytes
  // = 32 comps * (1024 m2 + 32 mus + 1 dn) * 4B = 135,296 B.
  const size_t fixed_b = (size_t)(32768 + 1024 + 32) * 4   // m2r/musr/dnr
                       + (size_t)(2 * n + 32) * 4          // wpair + pig
                       + (size_t)(n + 512) + 4096;         // zbuf + pad
  const size_t per_nb = 32ull * (1024 + 32 + 1) * 4;
  int NB = 512;
  if (ws_size < fixed_b + (size_t)NB * per_nb) {
    size_t avail = ws_size > fixed_b ? (ws_size - fixed_b) / per_nb : 8;
    NB = (int)(avail < 8 ? 8 : avail);
    if (NB > 512) NB = 512;
  }

  // ws layout: [m2p | musp | dnp | m2r | musr | dnr | wpair | pig | zbuf]
  float* m2p   = (float*)d_ws;                          // NB*32*1024
  float* musp  = m2p + (size_t)NB * 32 * 1024;          // NB*32*32
  float* dnp   = musp + (size_t)NB * 32 * 32;           // NB*32
  float* m2r   = dnp + (size_t)NB * 32;                 // 32768
  float* musr  = m2r + 32768;                           // 1024
  float* dnr   = musr + 1024;                           // 32
  float* wpair = dnr + 32;                              // 2n
  float* pig   = wpair + 2 * (size_t)n;                 // 32
  unsigned char* zbuf = (unsigned char*)(pig + 32);     // n + pad

  zero_k<<<1, 32, 0, stream>>>(pig, 32);
  prep_k<<<1024, 256, 0, stream>>>(r, ri, zbuf, wpair, pig, n);
  mstep_k<<<NB, 512, 0, stream>>>(X, zbuf, wpair, m2p, musp, dnp, n, nchunks);
  reduce_k<<<265, 256, 0, stream>>>(m2p, musp, dnp, m2r, musr, dnr, NB);
  finalize_k<<<32, 256, 0, stream>>>(pig, dnr, musr, m2r, out, n);
}